// Round 1
// baseline (347.321 us; speedup 1.0000x reference)
//
#include <hip/hip_runtime.h>

// Problem constants (fixed shapes from setup_inputs)
#define B_    8
#define C_    512
#define N_    1024          // H*W = 32*32
#define HEADS 8
#define DH    64            // E / heads
#define E_    512
#define M_QKV 1536          // 3*E

typedef _Float16 half8  __attribute__((ext_vector_type(8)));
typedef _Float16 half4  __attribute__((ext_vector_type(4)));
typedef __bf16   bf16x8 __attribute__((ext_vector_type(8)));
typedef __bf16   bf16x4 __attribute__((ext_vector_type(4)));
typedef float    f32x4  __attribute__((ext_vector_type(4)));

__device__ inline __bf16 f2bf(float f) {
    union { float f; unsigned u; } a; a.f = f;
    unsigned r = a.u + 0x7fffu + ((a.u >> 16) & 1u);   // RNE
    unsigned short h = (unsigned short)(r >> 16);
    union { unsigned short s; __bf16 b; } o; o.s = h;
    return o.b;
}

// ---------------- convert fp32 -> fp16 (weights) ----------------
__global__ void convert_w(const float* __restrict__ w, _Float16* __restrict__ o, int n) {
    int i = blockIdx.x * 256 + threadIdx.x;
    if (i < n) o[i] = (_Float16)w[i];
}

// ---------------- transpose x[b][c][n] -> xT[b][n][c] (fp16) ----------------
__global__ void transpose_x(const float* __restrict__ x, _Float16* __restrict__ xT) {
    __shared__ _Float16 tile[32][33];
    int b  = blockIdx.z;
    int n0 = blockIdx.x * 32, c0 = blockIdx.y * 32;
    int tx = threadIdx.x, ty = threadIdx.y;          // 32 x 8
    const float* xb = x + (size_t)b * C_ * N_;
    #pragma unroll
    for (int i = 0; i < 4; i++)
        tile[ty + 8*i][tx] = (_Float16)xb[(size_t)(c0 + ty + 8*i) * N_ + n0 + tx];
    __syncthreads();
    _Float16* xTb = xT + (size_t)b * N_ * C_;
    #pragma unroll
    for (int i = 0; i < 4; i++)
        xTb[(size_t)(n0 + ty + 8*i) * C_ + c0 + tx] = tile[tx][ty + 8*i];
}

// ---------------- QKV GEMM: qkv[o][n] = sum_c w_in[o][c] * x[b][c][n] ----------------
// A = w_in (row-major, fp16), B = xT[b] (n-major, fp16). 4 waves, each 16 rows x 64 cols.
// Epilogue scatters into qT/kT (n-major, *scale folded into q) and v (d-major, bf16).
__global__ __launch_bounds__(256) void qkv_gemm(
        const _Float16* __restrict__ w, const _Float16* __restrict__ xT,
        _Float16* __restrict__ qT, _Float16* __restrict__ kT, __bf16* __restrict__ v) {
    int b  = blockIdx.z;
    int m0 = blockIdx.y * 64;
    int n0 = blockIdx.x * 64;
    int wid = threadIdx.x >> 6, lane = threadIdx.x & 63;
    int hi = lane >> 4, li = lane & 15;

    const _Float16* arow = w + (size_t)(m0 + wid*16 + li) * C_;
    const _Float16* xb   = xT + (size_t)b * N_ * C_;

    f32x4 acc[4] = {};
    for (int kk = 0; kk < C_; kk += 32) {
        half8 af = *(const half8*)(arow + kk + hi*8);
        #pragma unroll
        for (int nf = 0; nf < 4; nf++) {
            half8 bfr = *(const half8*)(xb + (size_t)(n0 + nf*16 + li) * C_ + kk + hi*8);
            acc[nf] = __builtin_amdgcn_mfma_f32_16x16x32_f16(af, bfr, acc[nf], 0, 0, 0);
        }
    }

    int orow_base = m0 + wid*16 + hi*4;
    #pragma unroll
    for (int nf = 0; nf < 4; nf++) {
        int n = n0 + nf*16 + li;
        #pragma unroll
        for (int r = 0; r < 4; r++) {
            int orow = orow_base + r;
            int which = orow >> 9;          // 0=q 1=k 2=v (uniform per block)
            int rem = orow & 511;
            int h = rem >> 6, d = rem & 63;
            float val = acc[nf][r];
            size_t bh = (size_t)(b * HEADS + h);
            if (which == 0)      qT[(bh * N_ + n) * DH + d] = (_Float16)(val * 0.35355339059327373f);
            else if (which == 1) kT[(bh * N_ + n) * DH + d] = (_Float16)val;
            else                 v[(bh * DH + d) * N_ + n] = f2bf(val);
        }
    }
}

// ---------------- Attention: per (b,h), O[i][d] = softmax_a(q·k)[i][a] V[d][a] ----------------
// S^T = K^T Q  (M=a, N=i, K=d): D-layout gives lane -> P[a=hi*4+r + 16*af][i=li].
// Unnormalized softmax (no max subtraction; logits <= ~15), rsum in fp32, divide at end.
// PV: A-operand fed directly from P fragments (two-half k-slot convention), B = V rows (bf16).
__global__ __launch_bounds__(256) void attn_kernel(
        const _Float16* __restrict__ qT, const _Float16* __restrict__ kT,
        const __bf16* __restrict__ v, _Float16* __restrict__ oT) {
    int bh = blockIdx.y;                // b*8 + h
    int b = bh >> 3, h = bh & 7;
    int wid = threadIdx.x >> 6, lane = threadIdx.x & 63;
    int hi = lane >> 4, li = lane & 15;
    int i0 = blockIdx.x * 64 + wid * 16;

    const _Float16* q_s = qT + (size_t)bh * N_ * DH;
    const _Float16* k_s = kT + (size_t)bh * N_ * DH;
    const __bf16*   v_s = v  + (size_t)bh * DH * N_;

    // Q fragments (B-operand), loaded once: q[d][i] = qT[i][d]
    half8 qf0 = *(const half8*)(q_s + (size_t)(i0 + li) * DH + hi*8);
    half8 qf1 = *(const half8*)(q_s + (size_t)(i0 + li) * DH + 32 + hi*8);

    f32x4 o_acc[4] = {};
    float rsum = 0.f;

    for (int a0 = 0; a0 < N_; a0 += 64) {
        f32x4 s[4] = {};
        #pragma unroll
        for (int af = 0; af < 4; af++) {
            const _Float16* krow = k_s + (size_t)(a0 + af*16 + li) * DH;
            half8 kf0 = *(const half8*)(krow + hi*8);
            half8 kf1 = *(const half8*)(krow + 32 + hi*8);
            s[af] = __builtin_amdgcn_mfma_f32_16x16x32_f16(kf0, qf0, s[af], 0, 0, 0);
            s[af] = __builtin_amdgcn_mfma_f32_16x16x32_f16(kf1, qf1, s[af], 0, 0, 0);
        }
        // P = exp(S) (unnormalized), accumulate row-sum, pack PV A-fragments
        bf16x8 pa0, pa1;
        #pragma unroll
        for (int af = 0; af < 4; af++) {
            #pragma unroll
            for (int r = 0; r < 4; r++) {
                float pv = __expf(s[af][r]);
                rsum += pv;
                __bf16 pb = f2bf(pv);
                if (af < 2) pa0[af*4 + r] = pb;
                else        pa1[(af-2)*4 + r] = pb;
            }
        }
        // PV: B = v[d][a], two-half k-slots a = a0 + {hi*4+j, 16+hi*4+j, +32, +48}
        #pragma unroll
        for (int df = 0; df < 4; df++) {
            const __bf16* vrow = v_s + (size_t)(df*16 + li) * N_ + a0;
            bf16x4 t0 = *(const bf16x4*)(vrow + hi*4);
            bf16x4 t1 = *(const bf16x4*)(vrow + 16 + hi*4);
            bf16x8 vb0;
            #pragma unroll
            for (int j = 0; j < 4; j++) { vb0[j] = t0[j]; vb0[4+j] = t1[j]; }
            o_acc[df] = __builtin_amdgcn_mfma_f32_16x16x32_bf16(pa0, vb0, o_acc[df], 0, 0, 0);
            bf16x4 t2 = *(const bf16x4*)(vrow + 32 + hi*4);
            bf16x4 t3 = *(const bf16x4*)(vrow + 48 + hi*4);
            bf16x8 vb1;
            #pragma unroll
            for (int j = 0; j < 4; j++) { vb1[j] = t2[j]; vb1[4+j] = t3[j]; }
            o_acc[df] = __builtin_amdgcn_mfma_f32_16x16x32_bf16(pa1, vb1, o_acc[df], 0, 0, 0);
        }
    }

    // full row-sum per i = i0 + li (combine the 4 hi-groups)
    rsum += __shfl_xor(rsum, 16, 64);
    rsum += __shfl_xor(rsum, 32, 64);

    #pragma unroll
    for (int r = 0; r < 4; r++) {
        int il = hi*4 + r;
        float rs = __shfl(rsum, (lane & 48) | il, 64);
        float inv = 1.0f / rs;
        int n = i0 + il;
        #pragma unroll
        for (int df = 0; df < 4; df++) {
            oT[((size_t)b * N_ + n) * E_ + h*DH + df*16 + li] = (_Float16)(o_acc[df][r] * inv);
        }
    }
}

// ---------------- Output GEMM: out[c][n] = sum_e w_out[c][e]*oT[n][e] + b_out[c] + x[c][n] ----------------
__global__ __launch_bounds__(256) void out_gemm(
        const _Float16* __restrict__ w, const _Float16* __restrict__ oT,
        const float* __restrict__ bias, const float* __restrict__ x,
        float* __restrict__ out) {
    int b  = blockIdx.z;
    int c0 = blockIdx.y * 64;
    int n0 = blockIdx.x * 64;
    int wid = threadIdx.x >> 6, lane = threadIdx.x & 63;
    int hi = lane >> 4, li = lane & 15;

    const _Float16* arow = w + (size_t)(c0 + wid*16 + li) * E_;
    const _Float16* ob   = oT + (size_t)b * N_ * E_;

    f32x4 acc[4] = {};
    for (int kk = 0; kk < E_; kk += 32) {
        half8 af = *(const half8*)(arow + kk + hi*8);
        #pragma unroll
        for (int nf = 0; nf < 4; nf++) {
            half8 bfr = *(const half8*)(ob + (size_t)(n0 + nf*16 + li) * E_ + kk + hi*8);
            acc[nf] = __builtin_amdgcn_mfma_f32_16x16x32_f16(af, bfr, acc[nf], 0, 0, 0);
        }
    }

    int cb = c0 + wid*16 + hi*4;
    #pragma unroll
    for (int nf = 0; nf < 4; nf++) {
        int n = n0 + nf*16 + li;
        #pragma unroll
        for (int r = 0; r < 4; r++) {
            int c = cb + r;
            size_t idx = ((size_t)b * C_ + c) * N_ + n;
            out[idx] = acc[nf][r] + bias[c] + x[idx];
        }
    }
}

extern "C" void kernel_launch(void* const* d_in, const int* in_sizes, int n_in,
                              void* d_out, int out_size, void* d_ws, size_t ws_size,
                              hipStream_t stream) {
    const float* x     = (const float*)d_in[0];
    const float* w_in  = (const float*)d_in[1];
    const float* w_out = (const float*)d_in[2];
    const float* b_out = (const float*)d_in[3];
    float* out = (float*)d_out;

    // Workspace layout (total ~44 MB)
    char* ws = (char*)d_ws;
    _Float16* xT      = (_Float16*)ws; ws += (size_t)B_ * N_ * C_ * 2;        // 8 MB
    _Float16* w_in_h  = (_Float16*)ws; ws += (size_t)M_QKV * C_ * 2;          // 1.5 MB
    _Float16* w_out_h = (_Float16*)ws; ws += (size_t)C_ * E_ * 2;             // 0.5 MB
    _Float16* qT      = (_Float16*)ws; ws += (size_t)B_ * HEADS * N_ * DH * 2; // 8 MB
    _Float16* kT      = (_Float16*)ws; ws += (size_t)B_ * HEADS * N_ * DH * 2; // 8 MB
    __bf16*   v       = (__bf16*)ws;   ws += (size_t)B_ * HEADS * DH * N_ * 2; // 8 MB
    _Float16* oT      = (_Float16*)ws; ws += (size_t)B_ * N_ * E_ * 2;         // 8 MB

    convert_w<<<(M_QKV * C_ + 255) / 256, 256, 0, stream>>>(w_in, w_in_h, M_QKV * C_);
    convert_w<<<(C_ * E_ + 255) / 256, 256, 0, stream>>>(w_out, w_out_h, C_ * E_);
    transpose_x<<<dim3(N_ / 32, C_ / 32, B_), dim3(32, 8), 0, stream>>>(x, xT);

    qkv_gemm<<<dim3(N_ / 64, M_QKV / 64, B_), 256, 0, stream>>>(w_in_h, xT, qT, kT, v);
    attn_kernel<<<dim3(N_ / 64, B_ * HEADS), 256, 0, stream>>>(qT, kT, v, oT);
    out_gemm<<<dim3(N_ / 64, C_ / 64, B_), 256, 0, stream>>>(w_out_h, oT, b_out, x, out);
}

// Round 2
// 202.957 us; speedup vs baseline: 1.7113x; 1.7113x over previous
//
#include <hip/hip_runtime.h>

// Problem constants (fixed shapes from setup_inputs)
#define B_    8
#define C_    512
#define N_    1024          // H*W = 32*32
#define HEADS 8
#define DH    64            // E / heads
#define E_    512
#define M_QKV 1536          // 3*E

typedef _Float16 half8  __attribute__((ext_vector_type(8)));
typedef _Float16 half4  __attribute__((ext_vector_type(4)));
typedef __bf16   bf16x8 __attribute__((ext_vector_type(8)));
typedef __bf16   bf16x4 __attribute__((ext_vector_type(4)));
typedef float    f32x4  __attribute__((ext_vector_type(4)));

typedef __attribute__((address_space(3))) char lds_t;
typedef __attribute__((address_space(1))) char glb_t;

__device__ inline __bf16 f2bf(float f) {
    union { float f; unsigned u; } a; a.f = f;
    unsigned r = a.u + 0x7fffu + ((a.u >> 16) & 1u);   // RNE
    unsigned short h = (unsigned short)(r >> 16);
    union { unsigned short s; __bf16 b; } o; o.s = h;
    return o.b;
}

// ---------------- convert fp32 -> fp16 (weights) ----------------
__global__ void convert_w(const float* __restrict__ w, _Float16* __restrict__ o, int n) {
    int i = blockIdx.x * 256 + threadIdx.x;
    if (i < n) o[i] = (_Float16)w[i];
}

// ---------------- transpose x[b][c][n] -> xT[b][n][c] (fp16) ----------------
__global__ void transpose_x(const float* __restrict__ x, _Float16* __restrict__ xT) {
    __shared__ _Float16 tile[32][33];
    int b  = blockIdx.z;
    int n0 = blockIdx.x * 32, c0 = blockIdx.y * 32;
    int tx = threadIdx.x, ty = threadIdx.y;          // 32 x 8
    const float* xb = x + (size_t)b * C_ * N_;
    #pragma unroll
    for (int i = 0; i < 4; i++)
        tile[ty + 8*i][tx] = (_Float16)xb[(size_t)(c0 + ty + 8*i) * N_ + n0 + tx];
    __syncthreads();
    _Float16* xTb = xT + (size_t)b * N_ * C_;
    #pragma unroll
    for (int i = 0; i < 4; i++)
        xTb[(size_t)(n0 + ty + 8*i) * C_ + c0 + tx] = tile[tx][ty + 8*i];
}

// ---------------- QKV GEMM: qkv[o][n] = sum_c w_in[o][c] * x[b][c][n] ----------------
// V columns are written PRE-PERMUTED (bijective within each 32-block) so the attn
// PV B-operand "two-half k-slot" fragment is a contiguous 16B LDS read:
//   n' = (n&~31) | (((n>>2)&3)<<3) | (((n>>4)&1)<<2) | (n&3)
__global__ __launch_bounds__(256) void qkv_gemm(
        const _Float16* __restrict__ w, const _Float16* __restrict__ xT,
        _Float16* __restrict__ qT, _Float16* __restrict__ kT, __bf16* __restrict__ v) {
    int b  = blockIdx.z;
    int m0 = blockIdx.y * 64;
    int n0 = blockIdx.x * 64;
    int wid = threadIdx.x >> 6, lane = threadIdx.x & 63;
    int hi = lane >> 4, li = lane & 15;

    const _Float16* arow = w + (size_t)(m0 + wid*16 + li) * C_;
    const _Float16* xb   = xT + (size_t)b * N_ * C_;

    f32x4 acc[4] = {};
    for (int kk = 0; kk < C_; kk += 32) {
        half8 af = *(const half8*)(arow + kk + hi*8);
        #pragma unroll
        for (int nf = 0; nf < 4; nf++) {
            half8 bfr = *(const half8*)(xb + (size_t)(n0 + nf*16 + li) * C_ + kk + hi*8);
            acc[nf] = __builtin_amdgcn_mfma_f32_16x16x32_f16(af, bfr, acc[nf], 0, 0, 0);
        }
    }

    int orow_base = m0 + wid*16 + hi*4;
    #pragma unroll
    for (int nf = 0; nf < 4; nf++) {
        int n = n0 + nf*16 + li;
        int np = (n & ~31) | (((n >> 2) & 3) << 3) | (((n >> 4) & 1) << 2) | (n & 3);
        #pragma unroll
        for (int r = 0; r < 4; r++) {
            int orow = orow_base + r;
            int which = orow >> 9;          // 0=q 1=k 2=v (uniform per block)
            int rem = orow & 511;
            int h = rem >> 6, d = rem & 63;
            float val = acc[nf][r];
            size_t bh = (size_t)(b * HEADS + h);
            if (which == 0)      qT[(bh * N_ + n) * DH + d] = (_Float16)(val * 0.35355339059327373f);
            else if (which == 1) kT[(bh * N_ + n) * DH + d] = (_Float16)val;
            else                 v[(bh * DH + d) * N_ + np] = f2bf(val);
        }
    }
}

// ---------------- Attention (flash-style, LDS double-buffered) ----------------
// Per (b,h): S^T = K^T Q via MFMA (M=a, N=i). Unnormalized exp (no max-sub;
// logits <= ~20), fp32 row-sum, divide at end. K/V tiles (64x64) staged to LDS
// via global_load_lds w=16 with XOR-swizzled global source (rule #21);
// ds_read_b128 with matching swizzle on the read side.
__global__ __launch_bounds__(256) void attn_kernel(
        const _Float16* __restrict__ qT, const _Float16* __restrict__ kT,
        const __bf16* __restrict__ v, _Float16* __restrict__ oT) {
    __shared__ _Float16 kbuf[2][64*64];
    __shared__ __bf16   vbuf[2][64*64];

    int bh = blockIdx.y;                // b*8 + h
    int b = bh >> 3, h = bh & 7;
    int wid = threadIdx.x >> 6, lane = threadIdx.x & 63;
    int hi = lane >> 4, li = lane & 15;
    int i0 = blockIdx.x * 128 + wid * 32;     // 32 queries per wave

    const _Float16* q_s = qT + (size_t)bh * N_ * DH;
    const _Float16* k_s = kT + (size_t)bh * N_ * DH;
    const __bf16*   v_s = v  + (size_t)bh * DH * N_;

    // Q fragments (B-operand), loaded once: 2 i-groups x 2 d-halves
    half8 qf[2][2];
    #pragma unroll
    for (int ig = 0; ig < 2; ig++)
        #pragma unroll
        for (int hf = 0; hf < 2; hf++)
            qf[ig][hf] = *(const half8*)(q_s + (size_t)(i0 + ig*16 + li) * DH + hf*32 + hi*8);

    f32x4 o_acc[2][4] = {};
    float rsum[2] = {0.f, 0.f};

    int lr = lane >> 3;                 // staging: row within 8-row group
    int lc = 8 * ((lane & 7) ^ lr);     // pre-swizzled source column (elements)
    int swz = (li & 7) << 3;            // read-side XOR (elements)

    // prologue: stage tile a0=0 into buffer 0 (each wave: rows wid*16..+16)
    #pragma unroll
    for (int j = 0; j < 2; j++) {
        int row = wid*16 + j*8;
        __builtin_amdgcn_global_load_lds(
            (const glb_t*)(k_s + (size_t)(row + lr) * DH + lc),
            (lds_t*)&kbuf[0][row*64], 16, 0, 0);
        __builtin_amdgcn_global_load_lds(
            (const glb_t*)(v_s + (size_t)(row + lr) * N_ + lc),
            (lds_t*)&vbuf[0][row*64], 16, 0, 0);
    }
    __syncthreads();

    for (int t = 0; t < 16; t++) {
        int cb = t & 1;
        if (t < 15) {                   // stage next tile into other buffer
            int a1 = (t + 1) * 64;
            #pragma unroll
            for (int j = 0; j < 2; j++) {
                int row = wid*16 + j*8;
                __builtin_amdgcn_global_load_lds(
                    (const glb_t*)(k_s + (size_t)(a1 + row + lr) * DH + lc),
                    (lds_t*)&kbuf[cb^1][row*64], 16, 0, 0);
                __builtin_amdgcn_global_load_lds(
                    (const glb_t*)(v_s + (size_t)(row + lr) * N_ + a1 + lc),
                    (lds_t*)&vbuf[cb^1][row*64], 16, 0, 0);
            }
        }

        // ---- QK^T on current buffer: K fragments shared across both i-groups
        f32x4 s[2][4] = {};
        #pragma unroll
        for (int af = 0; af < 4; af++) {
            const _Float16* kr = &kbuf[cb][(af*16 + li) * 64];
            half8 kf0 = *(const half8*)(kr + ((hi*8) ^ swz));
            half8 kf1 = *(const half8*)(kr + ((32 + hi*8) ^ swz));
            #pragma unroll
            for (int ig = 0; ig < 2; ig++) {
                s[ig][af] = __builtin_amdgcn_mfma_f32_16x16x32_f16(kf0, qf[ig][0], s[ig][af], 0, 0, 0);
                s[ig][af] = __builtin_amdgcn_mfma_f32_16x16x32_f16(kf1, qf[ig][1], s[ig][af], 0, 0, 0);
            }
        }

        // ---- P = exp(S), pack to bf16 A-fragments via v_cvt_pk_bf16_f32
        bf16x8 pa[2][2];
        #pragma unroll
        for (int ig = 0; ig < 2; ig++) {
            float pv[16];
            #pragma unroll
            for (int af = 0; af < 4; af++)
                #pragma unroll
                for (int r = 0; r < 4; r++) {
                    float e = __expf(s[ig][af][r]);
                    pv[af*4 + r] = e;
                    rsum[ig] += e;
                }
            union { bf16x8 v8; unsigned u[4]; } u0, u1;
            #pragma unroll
            for (int w = 0; w < 4; w++) {
                asm("v_cvt_pk_bf16_f32 %0, %1, %2" : "=v"(u0.u[w]) : "v"(pv[w*2]),     "v"(pv[w*2+1]));
                asm("v_cvt_pk_bf16_f32 %0, %1, %2" : "=v"(u1.u[w]) : "v"(pv[8 + w*2]), "v"(pv[8 + w*2+1]));
            }
            pa[ig][0] = u0.v8;
            pa[ig][1] = u1.v8;
        }

        // ---- PV: V fragments (pre-permuted columns) shared across i-groups
        #pragma unroll
        for (int df = 0; df < 4; df++) {
            const __bf16* vr = &vbuf[cb][(df*16 + li) * 64];
            bf16x8 vb0 = *(const bf16x8*)(vr + ((hi*8) ^ swz));
            bf16x8 vb1 = *(const bf16x8*)(vr + ((32 + hi*8) ^ swz));
            #pragma unroll
            for (int ig = 0; ig < 2; ig++) {
                o_acc[ig][df] = __builtin_amdgcn_mfma_f32_16x16x32_bf16(pa[ig][0], vb0, o_acc[ig][df], 0, 0, 0);
                o_acc[ig][df] = __builtin_amdgcn_mfma_f32_16x16x32_bf16(pa[ig][1], vb1, o_acc[ig][df], 0, 0, 0);
            }
        }
        __syncthreads();
    }

    // normalize and write oT[b][n][h*64+d]
    #pragma unroll
    for (int ig = 0; ig < 2; ig++) {
        float rs = rsum[ig];
        rs += __shfl_xor(rs, 16, 64);
        rs += __shfl_xor(rs, 32, 64);
        #pragma unroll
        for (int r = 0; r < 4; r++) {
            int il = hi*4 + r;
            float den = __shfl(rs, (lane & 48) | il, 64);
            float inv = 1.0f / den;
            int n = i0 + ig*16 + il;
            #pragma unroll
            for (int df = 0; df < 4; df++)
                oT[((size_t)b * N_ + n) * E_ + h*DH + df*16 + li] = (_Float16)(o_acc[ig][df][r] * inv);
        }
    }
}

// ---------------- Output GEMM: out[c][n] = sum_e w_out[c][e]*oT[n][e] + b_out[c] + x[c][n] ----------------
__global__ __launch_bounds__(256) void out_gemm(
        const _Float16* __restrict__ w, const _Float16* __restrict__ oT,
        const float* __restrict__ bias, const float* __restrict__ x,
        float* __restrict__ out) {
    int b  = blockIdx.z;
    int c0 = blockIdx.y * 64;
    int n0 = blockIdx.x * 64;
    int wid = threadIdx.x >> 6, lane = threadIdx.x & 63;
    int hi = lane >> 4, li = lane & 15;

    const _Float16* arow = w + (size_t)(c0 + wid*16 + li) * E_;
    const _Float16* ob   = oT + (size_t)b * N_ * E_;

    f32x4 acc[4] = {};
    for (int kk = 0; kk < E_; kk += 32) {
        half8 af = *(const half8*)(arow + kk + hi*8);
        #pragma unroll
        for (int nf = 0; nf < 4; nf++) {
            half8 bfr = *(const half8*)(ob + (size_t)(n0 + nf*16 + li) * E_ + kk + hi*8);
            acc[nf] = __builtin_amdgcn_mfma_f32_16x16x32_f16(af, bfr, acc[nf], 0, 0, 0);
        }
    }

    int cb = c0 + wid*16 + hi*4;
    #pragma unroll
    for (int nf = 0; nf < 4; nf++) {
        int n = n0 + nf*16 + li;
        #pragma unroll
        for (int r = 0; r < 4; r++) {
            int c = cb + r;
            size_t idx = ((size_t)b * C_ + c) * N_ + n;
            out[idx] = acc[nf][r] + bias[c] + x[idx];
        }
    }
}

extern "C" void kernel_launch(void* const* d_in, const int* in_sizes, int n_in,
                              void* d_out, int out_size, void* d_ws, size_t ws_size,
                              hipStream_t stream) {
    const float* x     = (const float*)d_in[0];
    const float* w_in  = (const float*)d_in[1];
    const float* w_out = (const float*)d_in[2];
    const float* b_out = (const float*)d_in[3];
    float* out = (float*)d_out;

    // Workspace layout (total ~44 MB)
    char* ws = (char*)d_ws;
    _Float16* xT      = (_Float16*)ws; ws += (size_t)B_ * N_ * C_ * 2;        // 8 MB
    _Float16* w_in_h  = (_Float16*)ws; ws += (size_t)M_QKV * C_ * 2;          // 1.5 MB
    _Float16* w_out_h = (_Float16*)ws; ws += (size_t)C_ * E_ * 2;             // 0.5 MB
    _Float16* qT      = (_Float16*)ws; ws += (size_t)B_ * HEADS * N_ * DH * 2; // 8 MB
    _Float16* kT      = (_Float16*)ws; ws += (size_t)B_ * HEADS * N_ * DH * 2; // 8 MB
    __bf16*   v       = (__bf16*)ws;   ws += (size_t)B_ * HEADS * DH * N_ * 2; // 8 MB
    _Float16* oT      = (_Float16*)ws; ws += (size_t)B_ * N_ * E_ * 2;         // 8 MB

    convert_w<<<(M_QKV * C_ + 255) / 256, 256, 0, stream>>>(w_in, w_in_h, M_QKV * C_);
    convert_w<<<(C_ * E_ + 255) / 256, 256, 0, stream>>>(w_out, w_out_h, C_ * E_);
    transpose_x<<<dim3(N_ / 32, C_ / 32, B_), dim3(32, 8), 0, stream>>>(x, xT);

    qkv_gemm<<<dim3(N_ / 64, M_QKV / 64, B_), 256, 0, stream>>>(w_in_h, xT, qT, kT, v);
    attn_kernel<<<dim3(N_ / 128, B_ * HEADS), 256, 0, stream>>>(qT, kT, v, oT);
    out_gemm<<<dim3(N_ / 64, C_ / 64, B_), 256, 0, stream>>>(w_out_h, oT, b_out, x, out);
}

// Round 3
// 94.018 us; speedup vs baseline: 3.6942x; 2.1587x over previous
//
#include <hip/hip_runtime.h>

// Problem constants (fixed shapes from setup_inputs)
#define B_    8
#define C_    512
#define N_    1024          // H*W = 32*32
#define HEADS 8
#define DH    64            // E / heads
#define E_    512
#define M_QKV 1536          // 3*E

typedef _Float16 half8  __attribute__((ext_vector_type(8)));
typedef _Float16 half4  __attribute__((ext_vector_type(4)));
typedef __bf16   bf16x8 __attribute__((ext_vector_type(8)));
typedef __bf16   bf16x4 __attribute__((ext_vector_type(4)));
typedef float    f32x4  __attribute__((ext_vector_type(4)));

typedef __attribute__((address_space(3))) char lds_t;
typedef __attribute__((address_space(1))) char glb_t;

__device__ inline __bf16 f2bf(float f) {
    union { float f; unsigned u; } a; a.f = f;
    unsigned r = a.u + 0x7fffu + ((a.u >> 16) & 1u);   // RNE
    unsigned short h = (unsigned short)(r >> 16);
    union { unsigned short s; __bf16 b; } o; o.s = h;
    return o.b;
}

// ---------------- convert fp32 -> fp16 (weights) ----------------
__global__ void convert_w(const float* __restrict__ w, _Float16* __restrict__ o, int n) {
    int i = blockIdx.x * 256 + threadIdx.x;
    if (i < n) o[i] = (_Float16)w[i];
}

// ---------------- transpose x[b][c][n] -> xT[b][n][c] (fp16) ----------------
__global__ void transpose_x(const float* __restrict__ x, _Float16* __restrict__ xT) {
    __shared__ _Float16 tile[32][33];
    int b  = blockIdx.z;
    int n0 = blockIdx.x * 32, c0 = blockIdx.y * 32;
    int tx = threadIdx.x, ty = threadIdx.y;          // 32 x 8
    const float* xb = x + (size_t)b * C_ * N_;
    #pragma unroll
    for (int i = 0; i < 4; i++)
        tile[ty + 8*i][tx] = (_Float16)xb[(size_t)(c0 + ty + 8*i) * N_ + n0 + tx];
    __syncthreads();
    _Float16* xTb = xT + (size_t)b * N_ * C_;
    #pragma unroll
    for (int i = 0; i < 4; i++)
        xTb[(size_t)(n0 + ty + 8*i) * C_ + c0 + tx] = tile[tx][ty + 8*i];
}

// ============ shared 128x128xK main loop (BK=64, double-buffered LDS) ============
// A: [.][K] row-major starting at row m0; B: [.][K] row-major starting at row n0.
// 4 waves, wave (wr,wc) owns 64x64 output, acc[4][4] of 16x16 frags.
// Staging: global_load_lds w=16, source pre-swizzled (slot ^= row&7, 16B slots);
// reads XOR the same swizzle (verified pattern: +89% in attn-style tiles).
__device__ __forceinline__ void mm128_body(
        const _Float16* __restrict__ Abase, const _Float16* __restrict__ Bbase,
        int K, _Float16* abuf, _Float16* bbuf, f32x4 (&acc)[4][4]) {
    int tid = threadIdx.x;
    int wid = tid >> 6, lane = tid & 63;
    int hi = lane >> 4, li = lane & 15;
    int wr = wid >> 1, wc = wid & 1;
    int lr = lane >> 3, lslot = lane & 7;
    int srcoff = 8 * (lslot ^ lr);         // swizzled source chunk (elements)
    int swz = (li & 7) << 3;               // read-side XOR (elements)

    auto stage = [&](int buf, int kk) {
        #pragma unroll
        for (int j = 0; j < 4; j++) {
            int row = wid * 8 + j * 32;    // wave-uniform LDS base row
            __builtin_amdgcn_global_load_lds(
                (const glb_t*)(Abase + (size_t)(row + lr) * K + kk + srcoff),
                (lds_t*)(abuf + buf * (128*64) + row * 64), 16, 0, 0);
            __builtin_amdgcn_global_load_lds(
                (const glb_t*)(Bbase + (size_t)(row + lr) * K + kk + srcoff),
                (lds_t*)(bbuf + buf * (128*64) + row * 64), 16, 0, 0);
        }
    };

    stage(0, 0);
    __syncthreads();
    int nk = K >> 6;
    for (int kt = 0; kt < nk; kt++) {
        int cb = kt & 1;
        if (kt < nk - 1) stage(cb ^ 1, (kt + 1) * 64);
        #pragma unroll
        for (int ks = 0; ks < 2; ks++) {
            half8 a[4], bf[4];
            #pragma unroll
            for (int f = 0; f < 4; f++) {
                int koff = (ks * 32 + hi * 8) ^ swz;
                a[f]  = *(const half8*)(abuf + cb * (128*64) + (wr*64 + f*16 + li) * 64 + koff);
                bf[f] = *(const half8*)(bbuf + cb * (128*64) + (wc*64 + f*16 + li) * 64 + koff);
            }
            #pragma unroll
            for (int mf = 0; mf < 4; mf++)
                #pragma unroll
                for (int nf = 0; nf < 4; nf++)
                    acc[mf][nf] = __builtin_amdgcn_mfma_f32_16x16x32_f16(a[mf], bf[nf], acc[mf][nf], 0, 0, 0);
        }
        __syncthreads();
    }
}

// ---------------- QKV GEMM: qkv[o][n] = sum_c w_in[o][c] * x[b][c][n] ----------------
// V columns written PRE-PERMUTED: n' = (n&~31)|(((n>>2)&3)<<3)|(((n>>4)&1)<<2)|(n&3)
__global__ __launch_bounds__(256) void qkv_gemm(
        const _Float16* __restrict__ w, const _Float16* __restrict__ xT,
        _Float16* __restrict__ qT, _Float16* __restrict__ kT, __bf16* __restrict__ v) {
    __shared__ _Float16 abuf[2*128*64];
    __shared__ _Float16 bbuf[2*128*64];
    int b  = blockIdx.z;
    int m0 = blockIdx.y * 128;
    int n0 = blockIdx.x * 128;

    f32x4 acc[4][4] = {};
    mm128_body(w + (size_t)m0 * C_, xT + ((size_t)b * N_ + n0) * C_, C_, abuf, bbuf, acc);

    int wid = threadIdx.x >> 6, lane = threadIdx.x & 63;
    int hi = lane >> 4, li = lane & 15;
    int wr = wid >> 1, wc = wid & 1;
    int m_base = m0 + wr * 64, n_base = n0 + wc * 64;

    #pragma unroll
    for (int nf = 0; nf < 4; nf++) {
        int n = n_base + nf * 16 + li;
        int np = (n & ~31) | (((n >> 2) & 3) << 3) | (((n >> 4) & 1) << 2) | (n & 3);
        #pragma unroll
        for (int mf = 0; mf < 4; mf++) {
            #pragma unroll
            for (int r = 0; r < 4; r++) {
                int orow = m_base + mf * 16 + hi * 4 + r;
                int which = orow >> 9;          // 0=q 1=k 2=v (uniform per block)
                int rem = orow & 511;
                int h = rem >> 6, d = rem & 63;
                float val = acc[mf][nf][r];
                size_t bh = (size_t)(b * HEADS + h);
                if (which == 0)      qT[(bh * N_ + n) * DH + d] = (_Float16)(val * 0.35355339059327373f);
                else if (which == 1) kT[(bh * N_ + n) * DH + d] = (_Float16)val;
                else                 v[(bh * DH + d) * N_ + np] = f2bf(val);
            }
        }
    }
}

// ---------------- Attention (flash-style, LDS double-buffered) ----------------
__global__ __launch_bounds__(256) void attn_kernel(
        const _Float16* __restrict__ qT, const _Float16* __restrict__ kT,
        const __bf16* __restrict__ v, _Float16* __restrict__ oT) {
    __shared__ _Float16 kbuf[2][64*64];
    __shared__ __bf16   vbuf[2][64*64];

    int bh = blockIdx.y;                // b*8 + h
    int b = bh >> 3, h = bh & 7;
    int wid = threadIdx.x >> 6, lane = threadIdx.x & 63;
    int hi = lane >> 4, li = lane & 15;
    int i0 = blockIdx.x * 128 + wid * 32;     // 32 queries per wave

    const _Float16* q_s = qT + (size_t)bh * N_ * DH;
    const _Float16* k_s = kT + (size_t)bh * N_ * DH;
    const __bf16*   v_s = v  + (size_t)bh * DH * N_;

    half8 qf[2][2];
    #pragma unroll
    for (int ig = 0; ig < 2; ig++)
        #pragma unroll
        for (int hf = 0; hf < 2; hf++)
            qf[ig][hf] = *(const half8*)(q_s + (size_t)(i0 + ig*16 + li) * DH + hf*32 + hi*8);

    f32x4 o_acc[2][4] = {};
    float rsum[2] = {0.f, 0.f};

    int lr = lane >> 3;
    int lc = 8 * ((lane & 7) ^ lr);
    int swz = (li & 7) << 3;

    #pragma unroll
    for (int j = 0; j < 2; j++) {
        int row = wid*16 + j*8;
        __builtin_amdgcn_global_load_lds(
            (const glb_t*)(k_s + (size_t)(row + lr) * DH + lc),
            (lds_t*)&kbuf[0][row*64], 16, 0, 0);
        __builtin_amdgcn_global_load_lds(
            (const glb_t*)(v_s + (size_t)(row + lr) * N_ + lc),
            (lds_t*)&vbuf[0][row*64], 16, 0, 0);
    }
    __syncthreads();

    for (int t = 0; t < 16; t++) {
        int cb = t & 1;
        if (t < 15) {
            int a1 = (t + 1) * 64;
            #pragma unroll
            for (int j = 0; j < 2; j++) {
                int row = wid*16 + j*8;
                __builtin_amdgcn_global_load_lds(
                    (const glb_t*)(k_s + (size_t)(a1 + row + lr) * DH + lc),
                    (lds_t*)&kbuf[cb^1][row*64], 16, 0, 0);
                __builtin_amdgcn_global_load_lds(
                    (const glb_t*)(v_s + (size_t)(row + lr) * N_ + a1 + lc),
                    (lds_t*)&vbuf[cb^1][row*64], 16, 0, 0);
            }
        }

        f32x4 s[2][4] = {};
        #pragma unroll
        for (int af = 0; af < 4; af++) {
            const _Float16* kr = &kbuf[cb][(af*16 + li) * 64];
            half8 kf0 = *(const half8*)(kr + ((hi*8) ^ swz));
            half8 kf1 = *(const half8*)(kr + ((32 + hi*8) ^ swz));
            #pragma unroll
            for (int ig = 0; ig < 2; ig++) {
                s[ig][af] = __builtin_amdgcn_mfma_f32_16x16x32_f16(kf0, qf[ig][0], s[ig][af], 0, 0, 0);
                s[ig][af] = __builtin_amdgcn_mfma_f32_16x16x32_f16(kf1, qf[ig][1], s[ig][af], 0, 0, 0);
            }
        }

        bf16x8 pa[2][2];
        #pragma unroll
        for (int ig = 0; ig < 2; ig++) {
            float pv[16];
            #pragma unroll
            for (int af = 0; af < 4; af++)
                #pragma unroll
                for (int r = 0; r < 4; r++) {
                    float e = __expf(s[ig][af][r]);
                    pv[af*4 + r] = e;
                    rsum[ig] += e;
                }
            union { bf16x8 v8; unsigned u[4]; } u0, u1;
            #pragma unroll
            for (int w = 0; w < 4; w++) {
                asm("v_cvt_pk_bf16_f32 %0, %1, %2" : "=v"(u0.u[w]) : "v"(pv[w*2]),     "v"(pv[w*2+1]));
                asm("v_cvt_pk_bf16_f32 %0, %1, %2" : "=v"(u1.u[w]) : "v"(pv[8 + w*2]), "v"(pv[8 + w*2+1]));
            }
            pa[ig][0] = u0.v8;
            pa[ig][1] = u1.v8;
        }

        #pragma unroll
        for (int df = 0; df < 4; df++) {
            const __bf16* vr = &vbuf[cb][(df*16 + li) * 64];
            bf16x8 vb0 = *(const bf16x8*)(vr + ((hi*8) ^ swz));
            bf16x8 vb1 = *(const bf16x8*)(vr + ((32 + hi*8) ^ swz));
            #pragma unroll
            for (int ig = 0; ig < 2; ig++) {
                o_acc[ig][df] = __builtin_amdgcn_mfma_f32_16x16x32_bf16(pa[ig][0], vb0, o_acc[ig][df], 0, 0, 0);
                o_acc[ig][df] = __builtin_amdgcn_mfma_f32_16x16x32_bf16(pa[ig][1], vb1, o_acc[ig][df], 0, 0, 0);
            }
        }
        __syncthreads();
    }

    #pragma unroll
    for (int ig = 0; ig < 2; ig++) {
        float rs = rsum[ig];
        rs += __shfl_xor(rs, 16, 64);
        rs += __shfl_xor(rs, 32, 64);
        #pragma unroll
        for (int r = 0; r < 4; r++) {
            int il = hi*4 + r;
            float den = __shfl(rs, (lane & 48) | il, 64);
            float inv = 1.0f / den;
            int n = i0 + ig*16 + il;
            #pragma unroll
            for (int df = 0; df < 4; df++)
                oT[((size_t)b * N_ + n) * E_ + h*DH + df*16 + li] = (_Float16)(o_acc[ig][df][r] * inv);
        }
    }
}

// ---------------- Output GEMM: out[c][n] = sum_e w_out[c][e]*oT[n][e] + b_out[c] + x[c][n] ----------------
__global__ __launch_bounds__(256) void out_gemm(
        const _Float16* __restrict__ w, const _Float16* __restrict__ oT,
        const float* __restrict__ bias, const float* __restrict__ x,
        float* __restrict__ out) {
    __shared__ _Float16 abuf[2*128*64];
    __shared__ _Float16 bbuf[2*128*64];
    int b  = blockIdx.z;
    int c0 = blockIdx.y * 128;
    int n0 = blockIdx.x * 128;

    f32x4 acc[4][4] = {};
    mm128_body(w + (size_t)c0 * E_, oT + ((size_t)b * N_ + n0) * E_, E_, abuf, bbuf, acc);

    int wid = threadIdx.x >> 6, lane = threadIdx.x & 63;
    int hi = lane >> 4, li = lane & 15;
    int wr = wid >> 1, wc = wid & 1;
    int c_base = c0 + wr * 64, n_base = n0 + wc * 64;

    #pragma unroll
    for (int mf = 0; mf < 4; mf++) {
        #pragma unroll
        for (int nf = 0; nf < 4; nf++) {
            int n = n_base + nf * 16 + li;
            #pragma unroll
            for (int r = 0; r < 4; r++) {
                int c = c_base + mf * 16 + hi * 4 + r;
                size_t idx = ((size_t)b * C_ + c) * N_ + n;
                out[idx] = acc[mf][nf][r] + bias[c] + x[idx];
            }
        }
    }
}

extern "C" void kernel_launch(void* const* d_in, const int* in_sizes, int n_in,
                              void* d_out, int out_size, void* d_ws, size_t ws_size,
                              hipStream_t stream) {
    const float* x     = (const float*)d_in[0];
    const float* w_in  = (const float*)d_in[1];
    const float* w_out = (const float*)d_in[2];
    const float* b_out = (const float*)d_in[3];
    float* out = (float*)d_out;

    // Workspace layout (total ~44 MB)
    char* ws = (char*)d_ws;
    _Float16* xT      = (_Float16*)ws; ws += (size_t)B_ * N_ * C_ * 2;        // 8 MB
    _Float16* w_in_h  = (_Float16*)ws; ws += (size_t)M_QKV * C_ * 2;          // 1.5 MB
    _Float16* w_out_h = (_Float16*)ws; ws += (size_t)C_ * E_ * 2;             // 0.5 MB
    _Float16* qT      = (_Float16*)ws; ws += (size_t)B_ * HEADS * N_ * DH * 2; // 8 MB
    _Float16* kT      = (_Float16*)ws; ws += (size_t)B_ * HEADS * N_ * DH * 2; // 8 MB
    __bf16*   v       = (__bf16*)ws;   ws += (size_t)B_ * HEADS * DH * N_ * 2; // 8 MB
    _Float16* oT      = (_Float16*)ws; ws += (size_t)B_ * N_ * E_ * 2;         // 8 MB

    convert_w<<<(M_QKV * C_ + 255) / 256, 256, 0, stream>>>(w_in, w_in_h, M_QKV * C_);
    convert_w<<<(C_ * E_ + 255) / 256, 256, 0, stream>>>(w_out, w_out_h, C_ * E_);
    transpose_x<<<dim3(N_ / 32, C_ / 32, B_), dim3(32, 8), 0, stream>>>(x, xT);

    qkv_gemm<<<dim3(N_ / 128, M_QKV / 128, B_), 256, 0, stream>>>(w_in_h, xT, qT, kT, v);
    attn_kernel<<<dim3(N_ / 128, B_ * HEADS), 256, 0, stream>>>(qT, kT, v, oT);
    out_gemm<<<dim3(N_ / 128, C_ / 128, B_), 256, 0, stream>>>(w_out_h, oT, b_out, x, out);
}